// Round 18
// baseline (490.413 us; speedup 1.0000x reference)
//
#include <hip/hip_runtime.h>
#include <math.h>

// ContextualLoss via MFMA bf16.
// X,T = reshape(50,16384)[10:50]; S = Xn^T Tn (K=40 padded to 64, bf16 MFMA);
// per input-column i: m=min_j S, M=max_j S, Z=sum_j exp((1-S/(m+eps))/h);
// CXmax_i = max(w(m),w(M))/Z (w monotone in S); loss = -log(max_i CXmax_i).
//
// R18 = R17 (R11 template + atomic min/max tail) + ILP micro-opts in the
// jj loops ONLY (no sync-structure change, m152-safe):
//   1. explicit distance-2 B-frag prefetch (named regs, static indexing)
//   2. full unroll of the jj loop (addresses are base + jj*2048B, XOR slot
//      is jj-invariant since 16%8==0 -> folds into ds_read offsets)
//   3. s_setprio(1) around MFMA+epilogue (blocks on a SIMD are phase-skewed
//      -> role diversity, m191 regime, not m190's lockstep null)
// Rationale: occupancy/TLP axes measured-dead (R8/R9/R12/R13/R16); sumexp's
// VALU issue is ~90% useful (exp quarter-rate dominates); remaining slack is
// the 22% issue-idle from intra-wave ds_read->MFMA->epilogue chains. VGPR
// headroom (64 of 128 cap at 4 blocks/CU) makes deeper in-flight state free.

#define NCOL   16384
#define KDIM   40
#define KPAD   64
#define ROW0   10
#define EPSILON 1e-5f
#define COS_EPS 1e-8f
#define Q5L2E   7.2134752044448169f   // 5 * log2(e)  (1/h = 5)
#define JS      16                    // j slices
#define JSL     (NCOL / JS)           // 1024 j per slice
#define CHJ     128                   // j per staged chunk (16 KB)
#define NCH     (JSL / CHJ)           // 8 chunks per slice
#define TPC     (CHJ / 16)            // 8 16-wide j tiles per chunk

#if __has_builtin(__builtin_amdgcn_exp2f)
#define EXP2F(x) __builtin_amdgcn_exp2f(x)
#else
#define EXP2F(x) __expf((x) * 0.69314718055994531f)
#endif

typedef __attribute__((ext_vector_type(8))) short bf16x8;
typedef __attribute__((ext_vector_type(4))) float f32x4;

static __device__ __forceinline__ unsigned short f2bf(float f) {
    unsigned u = __float_as_uint(f);           // RNE float->bf16
    u += 0x7FFFu + ((u >> 16) & 1u);
    return (unsigned short)(u >> 16);
}

// order-preserving float<->uint encoding (f1<f2 <=> enc(f1)<enc(f2) unsigned)
static __device__ __forceinline__ unsigned encf(float f) {
    unsigned b = __float_as_uint(f);
    return (b & 0x80000000u) ? ~b : (b | 0x80000000u);
}
static __device__ __forceinline__ float decf(unsigned u) {
    return __uint_as_float((u & 0x80000000u) ? (u ^ 0x80000000u) : ~u);
}

// ---------------- kernel 1: mu + column normalize + bf16 pack + stat init --
// xb, tb: linear [n][64] bf16, k-padded with zeros. Re-inits rminE/rmaxE.
__global__ __launch_bounds__(256) void ctx_norm_kernel(
        const float* __restrict__ inp, const float* __restrict__ tgt,
        short* __restrict__ xb, short* __restrict__ tb,
        unsigned* __restrict__ rminE, unsigned* __restrict__ rmaxE) {
    int n = blockIdx.x * 256 + threadIdx.x;
    rminE[n] = 0xFFFFFFFFu;                    // enc(+inf) upper bound
    rmaxE[n] = 0u;                             // enc(-inf) lower bound
    float t[KDIM], x[KDIM];
    float mu = 0.f;
#pragma unroll
    for (int r = 0; r < KDIM; ++r) { t[r] = tgt[(ROW0 + r) * NCOL + n]; mu += t[r]; }
    mu *= (1.0f / KDIM);
    float nt = 0.f;
#pragma unroll
    for (int r = 0; r < KDIM; ++r) { t[r] -= mu; nt = fmaf(t[r], t[r], nt); }
    float rnt = 1.0f / fmaxf(sqrtf(nt), COS_EPS);
    float nx = 0.f;
#pragma unroll
    for (int r = 0; r < KDIM; ++r) {
        x[r] = inp[(ROW0 + r) * NCOL + n] - mu;
        nx = fmaf(x[r], x[r], nx);
    }
    float rnx = 1.0f / fmaxf(sqrtf(nx), COS_EPS);

    short* to = tb + (size_t)n * KPAD;
    short* xo = xb + (size_t)n * KPAD;
#pragma unroll
    for (int q = 0; q < KDIM / 4; ++q) {        // q = 0..9: data
        ushort4 wt, wx;
        wt.x = f2bf(t[4*q+0] * rnt); wt.y = f2bf(t[4*q+1] * rnt);
        wt.z = f2bf(t[4*q+2] * rnt); wt.w = f2bf(t[4*q+3] * rnt);
        wx.x = f2bf(x[4*q+0] * rnx); wx.y = f2bf(x[4*q+1] * rnx);
        wx.z = f2bf(x[4*q+2] * rnx); wx.w = f2bf(x[4*q+3] * rnx);
        *reinterpret_cast<ushort4*>(to + 4*q) = wt;
        *reinterpret_cast<ushort4*>(xo + 4*q) = wx;
    }
    ushort4 z = {0, 0, 0, 0};
#pragma unroll
    for (int q = KDIM / 4; q < KPAD / 4; ++q) { // q = 10..15: zero pad
        *reinterpret_cast<ushort4*>(to + 4*q) = z;
        *reinterpret_cast<ushort4*>(xo + 4*q) = z;
    }
}

// Staging (R11 template): chunk = CHJ rows x 128 B. Thread t moves 4 x 16 B:
// row = t/8 + r*32, slot = t&7. LDS swizzle: phys_slot = slot ^ (row & 7)
// on BOTH ds_write and ds_read (involution, rule #21).
#define STAGE_LOAD(st, src, tid)                                              \
    _Pragma("unroll")                                                         \
    for (int r_ = 0; r_ < 4; ++r_)                                            \
        (st)[r_] = *reinterpret_cast<const bf16x8*>((src) + (tid) * 8 + r_ * 2048);

#define STAGE_WRITE(buf, st, tid)                                             \
    {                                                                         \
        const int row_ = (tid) >> 3, s0_ = (tid) & 7;                         \
        _Pragma("unroll")                                                     \
        for (int r_ = 0; r_ < 4; ++r_) {                                      \
            int rr_ = row_ + r_ * 32;                                         \
            *reinterpret_cast<bf16x8*>(                                       \
                &(buf)[rr_ * 64 + ((s0_ ^ (rr_ & 7)) * 8)]) = (st)[r_];       \
        }                                                                     \
    }

// B-frag pair load for j-tile jj from buffer bufp (slot XOR jj-invariant)
#define LDB(bufp, jj, v0, v1)                                                 \
    {                                                                         \
        const short* lp_ = (bufp) + (jj) * 1024 + la * 64;                    \
        v0 = *reinterpret_cast<const bf16x8*>(lp_ + sxa);                     \
        v1 = *reinterpret_cast<const bf16x8*>(lp_ + sxb);                     \
    }

// ---------------- kernel 2: MFMA row min/max over a j slice ----------------
// grid (64, JS), 256 thr = 4 waves. Wave owns 64 i-rows (4 MFMA M-subtiles).
// B double-buffered in LDS (R11 protocol). C/D: col=lane&15, row=(lane>>4)*4+r.
// Publishes via deterministic atomicMin/Max on encoded uints.
__global__ __launch_bounds__(256, 4) void ctx_stats_kernel(
        const short* __restrict__ xb, const short* __restrict__ tb,
        unsigned* __restrict__ rminE, unsigned* __restrict__ rmaxE) {
    const int tid = threadIdx.x;
    const int wave = tid >> 6, l = tid & 63;
    const int la = l & 15, g = l >> 4;
    const int ibase = blockIdx.x * 256 + wave * 64;
    const int js = blockIdx.y;
    const int sxa = ((g    ) ^ (la & 7)) * 8;   // jj-invariant XOR slots
    const int sxb = ((g + 4) ^ (la & 7)) * 8;

    __shared__ __align__(16) short ldsb[2][CHJ * KPAD];   // 2 x 16 KB

    bf16x8 a[4][2];
#pragma unroll
    for (int mi = 0; mi < 4; ++mi)
#pragma unroll
        for (int ks = 0; ks < 2; ++ks)
            a[mi][ks] = *reinterpret_cast<const bf16x8*>(
                xb + (size_t)(ibase + mi * 16 + la) * KPAD + ks * 32 + g * 8);

    float vmn[4][4], vmx[4][4];
#pragma unroll
    for (int mi = 0; mi < 4; ++mi)
#pragma unroll
        for (int r = 0; r < 4; ++r) { vmn[mi][r] = 3.4e38f; vmx[mi][r] = -3.4e38f; }

    const short* tbase = tb + (size_t)js * JSL * KPAD;

    {   // prologue: stage chunk 0 into buffer 0
        bf16x8 st[4];
        STAGE_LOAD(st, tbase, tid);
        STAGE_WRITE(ldsb[0], st, tid);
    }
    __syncthreads();

    const f32x4 zero4 = {0.f, 0.f, 0.f, 0.f};
    int cb = 0;
    for (int ch = 0; ch < NCH; ++ch) {
        bf16x8 st[4];
        const bool more = (ch + 1 < NCH);
        if (more) {                       // issue next-chunk loads EARLY
            const short* src = tbase + (size_t)(ch + 1) * CHJ * KPAD;
            STAGE_LOAD(st, src, tid);
        }
        const short* bufp = &ldsb[cb][0];
        // distance-2 prefetched jj loop (named regs, static under unroll)
        bf16x8 c0, c1, n0, n1;
        LDB(bufp, 0, c0, c1);
        LDB(bufp, 1, n0, n1);
#pragma unroll
        for (int jj = 0; jj < TPC; ++jj) {
            __builtin_amdgcn_s_setprio(1);
#pragma unroll
            for (int mi = 0; mi < 4; ++mi) {
                f32x4 acc = __builtin_amdgcn_mfma_f32_16x16x32_bf16(a[mi][0], c0, zero4, 0, 0, 0);
                acc = __builtin_amdgcn_mfma_f32_16x16x32_bf16(a[mi][1], c1, acc, 0, 0, 0);
#pragma unroll
                for (int r = 0; r < 4; ++r) {
                    vmn[mi][r] = fminf(vmn[mi][r], acc[r]);
                    vmx[mi][r] = fmaxf(vmx[mi][r], acc[r]);
                }
            }
            __builtin_amdgcn_s_setprio(0);
            c0 = n0; c1 = n1;
            if (jj + 2 < TPC) LDB(bufp, jj + 2, n0, n1);
        }
        if (more) STAGE_WRITE(ldsb[cb ^ 1], st, tid);   // write LATE
        __syncthreads();
        cb ^= 1;
    }

    // reduce over the 16 column-lanes of each 16-lane group
#pragma unroll
    for (int off = 1; off < 16; off <<= 1)
#pragma unroll
        for (int mi = 0; mi < 4; ++mi)
#pragma unroll
            for (int r = 0; r < 4; ++r) {
                vmn[mi][r] = fminf(vmn[mi][r], __shfl_xor(vmn[mi][r], off, 64));
                vmx[mi][r] = fmaxf(vmx[mi][r], __shfl_xor(vmx[mi][r], off, 64));
            }
    if (la == 0) {
#pragma unroll
        for (int mi = 0; mi < 4; ++mi)
#pragma unroll
            for (int r = 0; r < 4; ++r) {
                int row = ibase + mi * 16 + g * 4 + r;
                atomicMin(&rminE[row], encf(vmn[mi][r]));
                atomicMax(&rmaxE[row], encf(vmx[mi][r]));
            }
    }
}

// ---------------- kernel 3: MFMA row sum of exp over a j slice ----------------
// w = exp((1-S*c)/h) = exp2(fma(S, -Q5L2E*c, Q5L2E)), c = 1/(m+eps) per row.
__global__ __launch_bounds__(256, 4) void ctx_sumexp_kernel(
        const short* __restrict__ xb, const short* __restrict__ tb,
        const unsigned* __restrict__ rminE, float* __restrict__ psum) {
    const int tid = threadIdx.x;
    const int wave = tid >> 6, l = tid & 63;
    const int la = l & 15, g = l >> 4;
    const int ibase = blockIdx.x * 256 + wave * 64;
    const int js = blockIdx.y;
    const int sxa = ((g    ) ^ (la & 7)) * 8;
    const int sxb = ((g + 4) ^ (la & 7)) * 8;

    __shared__ __align__(16) short ldsb[2][CHJ * KPAD];   // 2 x 16 KB

    bf16x8 a[4][2];
#pragma unroll
    for (int mi = 0; mi < 4; ++mi)
#pragma unroll
        for (int ks = 0; ks < 2; ++ks)
            a[mi][ks] = *reinterpret_cast<const bf16x8*>(
                xb + (size_t)(ibase + mi * 16 + la) * KPAD + ks * 32 + g * 8);

    float p[4][4], zs[4][4];
#pragma unroll
    for (int mi = 0; mi < 4; ++mi)
#pragma unroll
        for (int r = 0; r < 4; ++r) {
            int row = ibase + mi * 16 + g * 4 + r;
            float c = 1.0f / (decf(rminE[row]) + EPSILON);
            p[mi][r] = -Q5L2E * c;
            zs[mi][r] = 0.f;
        }

    const short* tbase = tb + (size_t)js * JSL * KPAD;

    {   // prologue: stage chunk 0 into buffer 0
        bf16x8 st[4];
        STAGE_LOAD(st, tbase, tid);
        STAGE_WRITE(ldsb[0], st, tid);
    }
    __syncthreads();

    const f32x4 zero4 = {0.f, 0.f, 0.f, 0.f};
    int cb = 0;
    for (int ch = 0; ch < NCH; ++ch) {
        bf16x8 st[4];
        const bool more = (ch + 1 < NCH);
        if (more) {                       // issue next-chunk loads EARLY
            const short* src = tbase + (size_t)(ch + 1) * CHJ * KPAD;
            STAGE_LOAD(st, src, tid);
        }
        const short* bufp = &ldsb[cb][0];
        bf16x8 c0, c1, n0, n1;
        LDB(bufp, 0, c0, c1);
        LDB(bufp, 1, n0, n1);
#pragma unroll
        for (int jj = 0; jj < TPC; ++jj) {
            __builtin_amdgcn_s_setprio(1);
#pragma unroll
            for (int mi = 0; mi < 4; ++mi) {
                f32x4 acc = __builtin_amdgcn_mfma_f32_16x16x32_bf16(a[mi][0], c0, zero4, 0, 0, 0);
                acc = __builtin_amdgcn_mfma_f32_16x16x32_bf16(a[mi][1], c1, acc, 0, 0, 0);
#pragma unroll
                for (int r = 0; r < 4; ++r)
                    zs[mi][r] += EXP2F(fmaf(acc[r], p[mi][r], Q5L2E));
            }
            __builtin_amdgcn_s_setprio(0);
            c0 = n0; c1 = n1;
            if (jj + 2 < TPC) LDB(bufp, jj + 2, n0, n1);
        }
        if (more) STAGE_WRITE(ldsb[cb ^ 1], st, tid);   // write LATE
        __syncthreads();
        cb ^= 1;
    }

#pragma unroll
    for (int off = 1; off < 16; off <<= 1)
#pragma unroll
        for (int mi = 0; mi < 4; ++mi)
#pragma unroll
            for (int r = 0; r < 4; ++r)
                zs[mi][r] += __shfl_xor(zs[mi][r], off, 64);
    if (la == 0) {
#pragma unroll
        for (int mi = 0; mi < 4; ++mi)
#pragma unroll
            for (int r = 0; r < 4; ++r) {
                int row = ibase + mi * 16 + g * 4 + r;
                psum[js * NCOL + row] = zs[mi][r];
            }
    }
}

// ---------------- kernel 4: per-row CX-max, per-block max ----------------
__global__ __launch_bounds__(256) void ctx_reduce_kernel(
        const unsigned* __restrict__ rminE, const unsigned* __restrict__ rmaxE,
        const float* __restrict__ psum, float* __restrict__ blkmax) {
    int tid = threadIdx.x;
    int i = blockIdx.x * 256 + tid;
    float m = decf(rminE[i]), M = decf(rmaxE[i]), Z = psum[i];
#pragma unroll
    for (int s = 1; s < JS; ++s) Z += psum[s * NCOL + i];
    float c = 1.0f / (m + EPSILON);
    float w1 = EXP2F(fmaf(M, -Q5L2E * c, Q5L2E));
    float w2 = EXP2F(fmaf(m, -Q5L2E * c, Q5L2E));
    float best = fmaxf(w1, w2) / Z;   // CX strictly positive

    for (int off = 32; off > 0; off >>= 1)
        best = fmaxf(best, __shfl_down(best, off, 64));
    __shared__ float red[4];
    if ((tid & 63) == 0) red[tid >> 6] = best;
    __syncthreads();
    if (tid == 0)
        blkmax[blockIdx.x] = fmaxf(fmaxf(red[0], red[1]), fmaxf(red[2], red[3]));
}

// ---------------- kernel 5: 64 -> 1, -log ----------------
__global__ void ctx_loss_kernel(const float* __restrict__ blkmax,
                                float* __restrict__ out) {
    int tid = threadIdx.x;       // one wave of 64
    float best = blkmax[tid];
    for (int off = 32; off > 0; off >>= 1)
        best = fmaxf(best, __shfl_down(best, off, 64));
    if (tid == 0) out[0] = -logf(best);
}

extern "C" void kernel_launch(void* const* d_in, const int* in_sizes, int n_in,
                              void* d_out, int out_size, void* d_ws, size_t ws_size,
                              hipStream_t stream) {
    const float* inp = (const float*)d_in[0];
    const float* tgt = (const float*)d_in[1];
    float* out = (float*)d_out;

    // ws layout (bytes):
    //   xb     bf16 [16384][64]  2 MB   (linear)
    //   tb     bf16 [16384][64]  2 MB   (linear)
    //   psum   f32  [16][16384]  1 MB
    //   rminE  u32  [16384]      64 KB  (order-preserving encoded)
    //   rmaxE  u32  [16384]      64 KB
    //   blkmax f32  [64]
    char* base = (char*)d_ws;
    short*    xb     = (short*)(base);
    short*    tb     = (short*)(base + (size_t)2 * NCOL * KPAD);        // +2MB
    float*    psum   = (float*)(base + (size_t)4 * NCOL * KPAD);        // +4MB
    unsigned* rminE  = (unsigned*)(psum + (size_t)JS * NCOL);
    unsigned* rmaxE  = rminE + NCOL;
    float*    blkmax = (float*)(rmaxE + NCOL);

    dim3 grid2(NCOL / 256, JS);
    ctx_norm_kernel  <<<NCOL / 256, 256, 0, stream>>>(inp, tgt, xb, tb, rminE, rmaxE);
    ctx_stats_kernel <<<grid2, 256, 0, stream>>>(xb, tb, rminE, rmaxE);
    ctx_sumexp_kernel<<<grid2, 256, 0, stream>>>(xb, tb, rminE, psum);
    ctx_reduce_kernel<<<NCOL / 256, 256, 0, stream>>>(rminE, rmaxE, psum, blkmax);
    ctx_loss_kernel  <<<1, 64, 0, stream>>>(blkmax, out);
}

// Round 19
// 94.190 us; speedup vs baseline: 5.2066x; 5.2066x over previous
//
#include <hip/hip_runtime.h>
#include <math.h>

// ContextualLoss via MFMA bf16.
// X,T = reshape(50,16384)[10:50]; S = Xn^T Tn (K=40 padded to 64, bf16 MFMA);
// per input-column i: m=min_j S, M=max_j S, Z=sum_j exp((1-S/(m+eps))/h);
// CXmax_i = max(w(m),w(M))/Z (w monotone in S); loss = -log(max_i CXmax_i).
//
// R19 = EXACT revert to R17 (best verified: 94.6 us). R18's ILP micro-opts
// (distance-2 B-prefetch + full unroll + setprio) pushed the live set past
// the allocator's hold and spilled staging state to scratch (487MB fetch /
// 693MB write per dispatch, VALUBusy 12%, 5x regression). Ledger: occupancy
// (R8/R9/R12/R13/R16), pipelining (R14/R15/R18), exp (R10), LDS staging
// (R11), tail (R17) -- all axes measured. Hot kernels at ~85% combined
// issue utilization; sumexp's VALU work ~90% irreducible (quarter-rate exp
// dominates). This is the structure's practical ceiling.

#define NCOL   16384
#define KDIM   40
#define KPAD   64
#define ROW0   10
#define EPSILON 1e-5f
#define COS_EPS 1e-8f
#define Q5L2E   7.2134752044448169f   // 5 * log2(e)  (1/h = 5)
#define JS      16                    // j slices
#define JSL     (NCOL / JS)           // 1024 j per slice
#define CHJ     128                   // j per staged chunk (16 KB)
#define NCH     (JSL / CHJ)           // 8 chunks per slice
#define TPC     (CHJ / 16)            // 8 16-wide j tiles per chunk

#if __has_builtin(__builtin_amdgcn_exp2f)
#define EXP2F(x) __builtin_amdgcn_exp2f(x)
#else
#define EXP2F(x) __expf((x) * 0.69314718055994531f)
#endif

typedef __attribute__((ext_vector_type(8))) short bf16x8;
typedef __attribute__((ext_vector_type(4))) float f32x4;

static __device__ __forceinline__ unsigned short f2bf(float f) {
    unsigned u = __float_as_uint(f);           // RNE float->bf16
    u += 0x7FFFu + ((u >> 16) & 1u);
    return (unsigned short)(u >> 16);
}

// order-preserving float<->uint encoding (f1<f2 <=> enc(f1)<enc(f2) unsigned)
static __device__ __forceinline__ unsigned encf(float f) {
    unsigned b = __float_as_uint(f);
    return (b & 0x80000000u) ? ~b : (b | 0x80000000u);
}
static __device__ __forceinline__ float decf(unsigned u) {
    return __uint_as_float((u & 0x80000000u) ? (u ^ 0x80000000u) : ~u);
}

// ---------------- kernel 1: mu + column normalize + bf16 pack + stat init --
// xb, tb: linear [n][64] bf16, k-padded with zeros. Re-inits rminE/rmaxE.
__global__ __launch_bounds__(256) void ctx_norm_kernel(
        const float* __restrict__ inp, const float* __restrict__ tgt,
        short* __restrict__ xb, short* __restrict__ tb,
        unsigned* __restrict__ rminE, unsigned* __restrict__ rmaxE) {
    int n = blockIdx.x * 256 + threadIdx.x;
    rminE[n] = 0xFFFFFFFFu;                    // enc(+inf) upper bound
    rmaxE[n] = 0u;                             // enc(-inf) lower bound
    float t[KDIM], x[KDIM];
    float mu = 0.f;
#pragma unroll
    for (int r = 0; r < KDIM; ++r) { t[r] = tgt[(ROW0 + r) * NCOL + n]; mu += t[r]; }
    mu *= (1.0f / KDIM);
    float nt = 0.f;
#pragma unroll
    for (int r = 0; r < KDIM; ++r) { t[r] -= mu; nt = fmaf(t[r], t[r], nt); }
    float rnt = 1.0f / fmaxf(sqrtf(nt), COS_EPS);
    float nx = 0.f;
#pragma unroll
    for (int r = 0; r < KDIM; ++r) {
        x[r] = inp[(ROW0 + r) * NCOL + n] - mu;
        nx = fmaf(x[r], x[r], nx);
    }
    float rnx = 1.0f / fmaxf(sqrtf(nx), COS_EPS);

    short* to = tb + (size_t)n * KPAD;
    short* xo = xb + (size_t)n * KPAD;
#pragma unroll
    for (int q = 0; q < KDIM / 4; ++q) {        // q = 0..9: data
        ushort4 wt, wx;
        wt.x = f2bf(t[4*q+0] * rnt); wt.y = f2bf(t[4*q+1] * rnt);
        wt.z = f2bf(t[4*q+2] * rnt); wt.w = f2bf(t[4*q+3] * rnt);
        wx.x = f2bf(x[4*q+0] * rnx); wx.y = f2bf(x[4*q+1] * rnx);
        wx.z = f2bf(x[4*q+2] * rnx); wx.w = f2bf(x[4*q+3] * rnx);
        *reinterpret_cast<ushort4*>(to + 4*q) = wt;
        *reinterpret_cast<ushort4*>(xo + 4*q) = wx;
    }
    ushort4 z = {0, 0, 0, 0};
#pragma unroll
    for (int q = KDIM / 4; q < KPAD / 4; ++q) { // q = 10..15: zero pad
        *reinterpret_cast<ushort4*>(to + 4*q) = z;
        *reinterpret_cast<ushort4*>(xo + 4*q) = z;
    }
}

// Staging (R11 template): chunk = CHJ rows x 128 B. Thread t moves 4 x 16 B:
// row = t/8 + r*32, slot = t&7. LDS swizzle: phys_slot = slot ^ (row & 7)
// on BOTH ds_write and ds_read (involution, rule #21).
#define STAGE_LOAD(st, src, tid)                                              \
    _Pragma("unroll")                                                         \
    for (int r_ = 0; r_ < 4; ++r_)                                            \
        (st)[r_] = *reinterpret_cast<const bf16x8*>((src) + (tid) * 8 + r_ * 2048);

#define STAGE_WRITE(buf, st, tid)                                             \
    {                                                                         \
        const int row_ = (tid) >> 3, s0_ = (tid) & 7;                         \
        _Pragma("unroll")                                                     \
        for (int r_ = 0; r_ < 4; ++r_) {                                      \
            int rr_ = row_ + r_ * 32;                                         \
            *reinterpret_cast<bf16x8*>(                                       \
                &(buf)[rr_ * 64 + ((s0_ ^ (rr_ & 7)) * 8)]) = (st)[r_];       \
        }                                                                     \
    }

// ---------------- kernel 2: MFMA row min/max over a j slice ----------------
// grid (64, JS), 256 thr = 4 waves. Wave owns 64 i-rows (4 MFMA M-subtiles).
// B double-buffered in LDS (R11 protocol). Read swizzle: slot = g ^ (row&7).
// C/D: col=lane&15, row=(lane>>4)*4+reg. Publishes via deterministic
// atomicMin/Max on encoded uints.
__global__ __launch_bounds__(256, 4) void ctx_stats_kernel(
        const short* __restrict__ xb, const short* __restrict__ tb,
        unsigned* __restrict__ rminE, unsigned* __restrict__ rmaxE) {
    const int tid = threadIdx.x;
    const int wave = tid >> 6, l = tid & 63;
    const int la = l & 15, g = l >> 4;
    const int ibase = blockIdx.x * 256 + wave * 64;
    const int js = blockIdx.y;

    __shared__ __align__(16) short ldsb[2][CHJ * KPAD];   // 2 x 16 KB

    bf16x8 a[4][2];
#pragma unroll
    for (int mi = 0; mi < 4; ++mi)
#pragma unroll
        for (int ks = 0; ks < 2; ++ks)
            a[mi][ks] = *reinterpret_cast<const bf16x8*>(
                xb + (size_t)(ibase + mi * 16 + la) * KPAD + ks * 32 + g * 8);

    float vmn[4][4], vmx[4][4];
#pragma unroll
    for (int mi = 0; mi < 4; ++mi)
#pragma unroll
        for (int r = 0; r < 4; ++r) { vmn[mi][r] = 3.4e38f; vmx[mi][r] = -3.4e38f; }

    const short* tbase = tb + (size_t)js * JSL * KPAD;

    {   // prologue: stage chunk 0 into buffer 0
        bf16x8 st[4];
        STAGE_LOAD(st, tbase, tid);
        STAGE_WRITE(ldsb[0], st, tid);
    }
    __syncthreads();

    const f32x4 zero4 = {0.f, 0.f, 0.f, 0.f};
    int cb = 0;
    for (int ch = 0; ch < NCH; ++ch) {
        bf16x8 st[4];
        const bool more = (ch + 1 < NCH);
        if (more) {                       // issue next-chunk loads EARLY
            const short* src = tbase + (size_t)(ch + 1) * CHJ * KPAD;
            STAGE_LOAD(st, src, tid);
        }
#pragma unroll 2
        for (int jj = 0; jj < TPC; ++jj) {
            const int lr = jj * 16 + la;
            const short* lp = &ldsb[cb][lr * 64];
            bf16x8 b0 = *reinterpret_cast<const bf16x8*>(lp + ((g    ) ^ (lr & 7)) * 8);
            bf16x8 b1 = *reinterpret_cast<const bf16x8*>(lp + ((g + 4) ^ (lr & 7)) * 8);
#pragma unroll
            for (int mi = 0; mi < 4; ++mi) {
                f32x4 acc = __builtin_amdgcn_mfma_f32_16x16x32_bf16(a[mi][0], b0, zero4, 0, 0, 0);
                acc = __builtin_amdgcn_mfma_f32_16x16x32_bf16(a[mi][1], b1, acc, 0, 0, 0);
#pragma unroll
                for (int r = 0; r < 4; ++r) {
                    vmn[mi][r] = fminf(vmn[mi][r], acc[r]);
                    vmx[mi][r] = fmaxf(vmx[mi][r], acc[r]);
                }
            }
        }
        if (more) STAGE_WRITE(ldsb[cb ^ 1], st, tid);   // write LATE
        __syncthreads();
        cb ^= 1;
    }

    // reduce over the 16 column-lanes of each 16-lane group
#pragma unroll
    for (int off = 1; off < 16; off <<= 1)
#pragma unroll
        for (int mi = 0; mi < 4; ++mi)
#pragma unroll
            for (int r = 0; r < 4; ++r) {
                vmn[mi][r] = fminf(vmn[mi][r], __shfl_xor(vmn[mi][r], off, 64));
                vmx[mi][r] = fmaxf(vmx[mi][r], __shfl_xor(vmx[mi][r], off, 64));
            }
    if (la == 0) {
#pragma unroll
        for (int mi = 0; mi < 4; ++mi)
#pragma unroll
            for (int r = 0; r < 4; ++r) {
                int row = ibase + mi * 16 + g * 4 + r;
                atomicMin(&rminE[row], encf(vmn[mi][r]));
                atomicMax(&rmaxE[row], encf(vmx[mi][r]));
            }
    }
}

// ---------------- kernel 3: MFMA row sum of exp over a j slice ----------------
// w = exp((1-S*c)/h) = exp2(fma(S, -Q5L2E*c, Q5L2E)), c = 1/(m+eps) per row.
__global__ __launch_bounds__(256, 4) void ctx_sumexp_kernel(
        const short* __restrict__ xb, const short* __restrict__ tb,
        const unsigned* __restrict__ rminE, float* __restrict__ psum) {
    const int tid = threadIdx.x;
    const int wave = tid >> 6, l = tid & 63;
    const int la = l & 15, g = l >> 4;
    const int ibase = blockIdx.x * 256 + wave * 64;
    const int js = blockIdx.y;

    __shared__ __align__(16) short ldsb[2][CHJ * KPAD];   // 2 x 16 KB

    bf16x8 a[4][2];
#pragma unroll
    for (int mi = 0; mi < 4; ++mi)
#pragma unroll
        for (int ks = 0; ks < 2; ++ks)
            a[mi][ks] = *reinterpret_cast<const bf16x8*>(
                xb + (size_t)(ibase + mi * 16 + la) * KPAD + ks * 32 + g * 8);

    float p[4][4], zs[4][4];
#pragma unroll
    for (int mi = 0; mi < 4; ++mi)
#pragma unroll
        for (int r = 0; r < 4; ++r) {
            int row = ibase + mi * 16 + g * 4 + r;
            float c = 1.0f / (decf(rminE[row]) + EPSILON);
            p[mi][r] = -Q5L2E * c;
            zs[mi][r] = 0.f;
        }

    const short* tbase = tb + (size_t)js * JSL * KPAD;

    {   // prologue: stage chunk 0 into buffer 0
        bf16x8 st[4];
        STAGE_LOAD(st, tbase, tid);
        STAGE_WRITE(ldsb[0], st, tid);
    }
    __syncthreads();

    const f32x4 zero4 = {0.f, 0.f, 0.f, 0.f};
    int cb = 0;
    for (int ch = 0; ch < NCH; ++ch) {
        bf16x8 st[4];
        const bool more = (ch + 1 < NCH);
        if (more) {                       // issue next-chunk loads EARLY
            const short* src = tbase + (size_t)(ch + 1) * CHJ * KPAD;
            STAGE_LOAD(st, src, tid);
        }
#pragma unroll 2
        for (int jj = 0; jj < TPC; ++jj) {
            const int lr = jj * 16 + la;
            const short* lp = &ldsb[cb][lr * 64];
            bf16x8 b0 = *reinterpret_cast<const bf16x8*>(lp + ((g    ) ^ (lr & 7)) * 8);
            bf16x8 b1 = *reinterpret_cast<const bf16x8*>(lp + ((g + 4) ^ (lr & 7)) * 8);
#pragma unroll
            for (int mi = 0; mi < 4; ++mi) {
                f32x4 acc = __builtin_amdgcn_mfma_f32_16x16x32_bf16(a[mi][0], b0, zero4, 0, 0, 0);
                acc = __builtin_amdgcn_mfma_f32_16x16x32_bf16(a[mi][1], b1, acc, 0, 0, 0);
#pragma unroll
                for (int r = 0; r < 4; ++r)
                    zs[mi][r] += EXP2F(fmaf(acc[r], p[mi][r], Q5L2E));
            }
        }
        if (more) STAGE_WRITE(ldsb[cb ^ 1], st, tid);   // write LATE
        __syncthreads();
        cb ^= 1;
    }

#pragma unroll
    for (int off = 1; off < 16; off <<= 1)
#pragma unroll
        for (int mi = 0; mi < 4; ++mi)
#pragma unroll
            for (int r = 0; r < 4; ++r)
                zs[mi][r] += __shfl_xor(zs[mi][r], off, 64);
    if (la == 0) {
#pragma unroll
        for (int mi = 0; mi < 4; ++mi)
#pragma unroll
            for (int r = 0; r < 4; ++r) {
                int row = ibase + mi * 16 + g * 4 + r;
                psum[js * NCOL + row] = zs[mi][r];
            }
    }
}

// ---------------- kernel 4: per-row CX-max, per-block max ----------------
__global__ __launch_bounds__(256) void ctx_reduce_kernel(
        const unsigned* __restrict__ rminE, const unsigned* __restrict__ rmaxE,
        const float* __restrict__ psum, float* __restrict__ blkmax) {
    int tid = threadIdx.x;
    int i = blockIdx.x * 256 + tid;
    float m = decf(rminE[i]), M = decf(rmaxE[i]), Z = psum[i];
#pragma unroll
    for (int s = 1; s < JS; ++s) Z += psum[s * NCOL + i];
    float c = 1.0f / (m + EPSILON);
    float w1 = EXP2F(fmaf(M, -Q5L2E * c, Q5L2E));
    float w2 = EXP2F(fmaf(m, -Q5L2E * c, Q5L2E));
    float best = fmaxf(w1, w2) / Z;   // CX strictly positive

    for (int off = 32; off > 0; off >>= 1)
        best = fmaxf(best, __shfl_down(best, off, 64));
    __shared__ float red[4];
    if ((tid & 63) == 0) red[tid >> 6] = best;
    __syncthreads();
    if (tid == 0)
        blkmax[blockIdx.x] = fmaxf(fmaxf(red[0], red[1]), fmaxf(red[2], red[3]));
}

// ---------------- kernel 5: 64 -> 1, -log ----------------
__global__ void ctx_loss_kernel(const float* __restrict__ blkmax,
                                float* __restrict__ out) {
    int tid = threadIdx.x;       // one wave of 64
    float best = blkmax[tid];
    for (int off = 32; off > 0; off >>= 1)
        best = fmaxf(best, __shfl_down(best, off, 64));
    if (tid == 0) out[0] = -logf(best);
}

extern "C" void kernel_launch(void* const* d_in, const int* in_sizes, int n_in,
                              void* d_out, int out_size, void* d_ws, size_t ws_size,
                              hipStream_t stream) {
    const float* inp = (const float*)d_in[0];
    const float* tgt = (const float*)d_in[1];
    float* out = (float*)d_out;

    // ws layout (bytes):
    //   xb     bf16 [16384][64]  2 MB   (linear)
    //   tb     bf16 [16384][64]  2 MB   (linear)
    //   psum   f32  [16][16384]  1 MB
    //   rminE  u32  [16384]      64 KB  (order-preserving encoded)
    //   rmaxE  u32  [16384]      64 KB
    //   blkmax f32  [64]
    char* base = (char*)d_ws;
    short*    xb     = (short*)(base);
    short*    tb     = (short*)(base + (size_t)2 * NCOL * KPAD);        // +2MB
    float*    psum   = (float*)(base + (size_t)4 * NCOL * KPAD);        // +4MB
    unsigned* rminE  = (unsigned*)(psum + (size_t)JS * NCOL);
    unsigned* rmaxE  = rminE + NCOL;
    float*    blkmax = (float*)(rmaxE + NCOL);

    dim3 grid2(NCOL / 256, JS);
    ctx_norm_kernel  <<<NCOL / 256, 256, 0, stream>>>(inp, tgt, xb, tb, rminE, rmaxE);
    ctx_stats_kernel <<<grid2, 256, 0, stream>>>(xb, tb, rminE, rmaxE);
    ctx_sumexp_kernel<<<grid2, 256, 0, stream>>>(xb, tb, rminE, psum);
    ctx_reduce_kernel<<<NCOL / 256, 256, 0, stream>>>(rminE, rmaxE, psum, blkmax);
    ctx_loss_kernel  <<<1, 64, 0, stream>>>(blkmax, out);
}